// Round 5
// baseline (247.290 us; speedup 1.0000x reference)
//
#include <hip/hip_runtime.h>
#include <hip/hip_bf16.h>
#include <stdint.h>

#define BM 128
#define BN 128

typedef __attribute__((ext_vector_type(8))) short bf16x8;
typedef __attribute__((ext_vector_type(4))) float f32x4;
typedef __attribute__((ext_vector_type(4))) uint32_t u32x4;

__device__ __forceinline__ short f2bf(float f) {
  union { float f; uint32_t u; } v; v.f = f;
  return (short)((v.u + 0x7FFFu + ((v.u >> 16) & 1u)) >> 16);  // RNE
}
__device__ __forceinline__ float bf2f(uint16_t s) {
  union { uint32_t u; float f; } v; v.u = ((uint32_t)s) << 16;
  return v.f;
}
__device__ __forceinline__ uint32_t pk2(float lo, float hi) {
  union { __hip_bfloat162 h; uint32_t u; } un;
  un.h = __float22bfloat162_rn(make_float2(lo, hi));  // v_cvt_pk_bf16_f32
  return un.u;
}
__device__ __forceinline__ void gload_lds16(const void* g, void* l) {
  __builtin_amdgcn_global_load_lds((const __attribute__((address_space(1))) void*)g,
                                   (__attribute__((address_space(3))) void*)l, 16, 0, 0);
}
// bijective XCD-chunk swizzle (m204)
__device__ __forceinline__ int xcd_swz(int d, int n) {
  const int q = n >> 3, r = n & 7, x = d & 7, i = d >> 3;
  return (x < r ? x * (q + 1) : r * (q + 1) + (x - r) * q) + i;
}

enum { A_LDS = 0, A_REG = 1, A_REGGATHER = 2 };
enum { E_PLAIN16 = 0, E_EDGE = 1, E_NODE = 2, E_PRED = 3 };

struct GemmArgs {
  const uint16_t* Ab; int lda;   // A_LDS: bf16 A
  const float* Af;               // A_REG*: fp32 A (lda=512)
  const int* gidx;               // row gather (A_REGGATHER)
  const uint16_t* B0;            // B^T bf16 [N][K]; out cols < 512
  const uint16_t* B1;            // out cols >= 512
  int K;
  int nwg, ncol;                 // 1-D grid decomposition (col-fastest)
  uint16_t* C16; int ldc;        // bf16 output
  const float* bias;
  const float* wattn;
  const int* src; const int* dst; const int* toe;
  const uint16_t* A13;           // bf16 [4096][1024]
  const uint16_t* U13;           // bf16 [4096][1024]
  uint16_t* EF;                  // e_f bf16 [61440][512]
  float* AATT;                   // attn partials [61440]
  float* OUT;                    // pred fp32 [3840][512]
};

// K-step 64 (two [128][32] halves per buffer), double-buffered, 2-phase prefetch:
//   stage(t+1) -> compute(t) -> __syncthreads  (one barrier per K-step)
template <int AMODE, int EPI>
__global__ __launch_bounds__(256) void gemm_k(GemmArgs g) {
  __shared__ __align__(16) short As[2][8192];  // [buf][h*4096 + row*32 + k]
  __shared__ __align__(16) short Bs[2][8192];
  const int tid = threadIdx.x, w = tid >> 6, lane = tid & 63;

  const int sid = xcd_swz(blockIdx.x, g.nwg);
  const int colb = sid % g.ncol, rowb = sid / g.ncol;
  const int m0 = rowb * BM, n0g = colb * BN;

  const uint16_t* Bp = g.B0; int n0 = n0g;
  if (n0g >= 512) { Bp = g.B1; n0 = n0g - 512; }

  const int NT = g.K >> 6;

  // ---- global_load_lds geometry (16B/lane, linear dest) ----
  const int gr = lane >> 2, gk = (lane & 3) * 8;
  const uint16_t* gB0 = Bp + (size_t)(n0 + w * 16 + gr) * g.K + gk;
  const uint16_t* gB1 = gB0 + (size_t)64 * g.K;
  const int cofs0 = (w * 16) * 32;
  const int cofs1 = (64 + w * 16) * 32;

  const uint16_t* gA0 = nullptr; const uint16_t* gA1 = nullptr;
  const float* arow = nullptr; int aofs = 0;
  if constexpr (AMODE == A_LDS) {
    gA0 = g.Ab + (size_t)(m0 + w * 16 + gr) * g.lda + gk;
    gA1 = gA0 + (size_t)64 * g.lda;
  } else {
    const int tr = tid >> 1, ch = tid & 1;
    int row = m0 + tr;
    if constexpr (AMODE == A_REGGATHER) row = g.gidx[row];
    arow = g.Af + (size_t)row * 512 + ch * 16;
    aofs = tr * 32 + ch * 16;
  }

  auto stage = [&](int t, int buf) {  // B always; A too in LDS mode
    const int kk = t * 64;
#pragma unroll
    for (int h = 0; h < 2; ++h) {
      const int k2 = kk + h * 32;
      gload_lds16(gB0 + k2, &Bs[buf][h * 4096 + cofs0]);
      gload_lds16(gB1 + k2, &Bs[buf][h * 4096 + cofs1]);
      if constexpr (AMODE == A_LDS) {
        gload_lds16(gA0 + k2, &As[buf][h * 4096 + cofs0]);
        gload_lds16(gA1 + k2, &As[buf][h * 4096 + cofs1]);
      }
    }
  };
  auto loadA = [&](float4* S, int t) {  // 32 fp32 -> regs (cols t*64 + h*32 + ch*16 ..)
    const float* p = arow + t * 64;
#pragma unroll
    for (int h = 0; h < 2; ++h)
#pragma unroll
      for (int i = 0; i < 4; ++i) S[h * 4 + i] = *(const float4*)(p + h * 32 + i * 4);
  };
  auto writeA = [&](const float4* S, int buf) {
#pragma unroll
    for (int h = 0; h < 2; ++h) {
      u32x4 q0, q1;
      q0[0] = pk2(S[h*4+0].x, S[h*4+0].y); q0[1] = pk2(S[h*4+0].z, S[h*4+0].w);
      q0[2] = pk2(S[h*4+1].x, S[h*4+1].y); q0[3] = pk2(S[h*4+1].z, S[h*4+1].w);
      q1[0] = pk2(S[h*4+2].x, S[h*4+2].y); q1[1] = pk2(S[h*4+2].z, S[h*4+2].w);
      q1[2] = pk2(S[h*4+3].x, S[h*4+3].y); q1[3] = pk2(S[h*4+3].z, S[h*4+3].w);
      *(u32x4*)&As[buf][h * 4096 + aofs] = q0;
      *(u32x4*)&As[buf][h * 4096 + aofs + 8] = q1;
    }
  };

  const int wm = w >> 1, wn = w & 1;
  const int lr = lane & 15, lg = lane >> 4;
  int aro[4], bro[4];
#pragma unroll
  for (int m = 0; m < 4; ++m) aro[m] = (wm * 64 + m * 16 + lr) * 32 + lg * 8;
#pragma unroll
  for (int n = 0; n < 4; ++n) bro[n] = (wn * 64 + n * 16 + lr) * 32 + lg * 8;

  f32x4 acc[4][4] = {};
  float4 S[8];

  // ---- prologue: stage tile 0 into buf0 ----
  stage(0, 0);
  if constexpr (AMODE != A_LDS) { loadA(S, 0); writeA(S, 0); }
  __syncthreads();

  for (int t = 0; t < NT; ++t) {
    const int cur = t & 1, nxt = cur ^ 1;
    const int tn = (t + 1 < NT) ? t + 1 : t;
    stage(tn, nxt);                        // prefetch next tile (B [+A] glds)
    if constexpr (AMODE != A_LDS) loadA(S, tn);  // A(t+1) -> regs, overlaps compute
#pragma unroll
    for (int h = 0; h < 2; ++h) {
      bf16x8 av[4], bv[4];
#pragma unroll
      for (int m = 0; m < 4; ++m) av[m] = *(const bf16x8*)&As[cur][h * 4096 + aro[m]];
#pragma unroll
      for (int n = 0; n < 4; ++n) bv[n] = *(const bf16x8*)&Bs[cur][h * 4096 + bro[n]];
#pragma unroll
      for (int m = 0; m < 4; ++m)
#pragma unroll
        for (int n = 0; n < 4; ++n)
          acc[m][n] = __builtin_amdgcn_mfma_f32_16x16x32_bf16(av[m], bv[n], acc[m][n], 0, 0, 0);
    }
    if constexpr (AMODE != A_LDS) writeA(S, nxt);  // cvt+ds_write after compute
    __syncthreads();                                // drains stage glds + lds
  }

  // ---- epilogue ----  C/D: col = lane&15, row = (lane>>4)*4 + reg
  const int rbase = m0 + wm * 64;
  const int cbase = n0g + wn * 64;

  if constexpr (EPI == E_PLAIN16) {
#pragma unroll
    for (int m = 0; m < 4; ++m)
#pragma unroll
      for (int r = 0; r < 4; ++r) {
        const int row = rbase + m * 16 + lg * 4 + r;
#pragma unroll
        for (int n = 0; n < 4; ++n)
          g.C16[(size_t)row * g.ldc + cbase + n * 16 + lr] = (uint16_t)f2bf(acc[m][n][r]);
      }
  } else if constexpr (EPI == E_NODE) {
#pragma unroll
    for (int m = 0; m < 4; ++m)
#pragma unroll
      for (int r = 0; r < 4; ++r) {
        const int row = rbase + m * 16 + lg * 4 + r;
#pragma unroll
        for (int n = 0; n < 4; ++n) {
          const int col = cbase + n * 16 + lr;
          const float v = fmaxf(acc[m][n][r] + g.bias[col], 0.f);
          g.C16[(size_t)row * g.ldc + col] = (uint16_t)f2bf(v);
        }
      }
  } else if constexpr (EPI == E_EDGE) {
    float bv[4], wv[4]; int cols[4];
#pragma unroll
    for (int n = 0; n < 4; ++n) {
      cols[n] = cbase + n * 16 + lr;
      bv[n] = g.bias[cols[n]];
      wv[n] = g.wattn[cols[n]];
    }
#pragma unroll
    for (int m = 0; m < 4; ++m)
#pragma unroll
      for (int r = 0; r < 4; ++r) {
        const int e = rbase + m * 16 + lg * 4 + r;
        const int se = g.src[e], de = g.dst[e];
        const uint16_t* a1 = g.A13 + (size_t)se * 1024;
        const uint16_t* a3 = g.A13 + (size_t)de * 1024 + 512;
        float rp = 0.f;
#pragma unroll
        for (int n = 0; n < 4; ++n) {
          float v = acc[m][n][r] + bf2f(a1[cols[n]]) + bf2f(a3[cols[n]]) + bv[n];
          v = fmaxf(v, 0.f);
          rp += v * wv[n];
          g.EF[(size_t)e * 512 + cols[n]] = (uint16_t)f2bf(v);
        }
        for (int d = 1; d < 16; d <<= 1) rp += __shfl_xor(rp, d);
        if (lr == 0) atomicAdd(&g.AATT[e], rp);
      }
  } else {  // E_PRED
    float bv[4]; int cols[4];
#pragma unroll
    for (int n = 0; n < 4; ++n) { cols[n] = cbase + n * 16 + lr; bv[n] = g.bias[cols[n]]; }
#pragma unroll
    for (int m = 0; m < 4; ++m)
#pragma unroll
      for (int r = 0; r < 4; ++r) {
        const int row = rbase + m * 16 + lg * 4 + r;
        const int te = g.toe[row];
        const int ts = g.src[te], td = g.dst[te];
        const uint16_t* u1 = g.U13 + (size_t)ts * 1024;
        const uint16_t* u3 = g.U13 + (size_t)td * 1024 + 512;
#pragma unroll
        for (int n = 0; n < 4; ++n) {
          const float v = acc[m][n][r] + bf2f(u1[cols[n]]) + bf2f(u3[cols[n]]) + bv[n];
          g.OUT[(size_t)row * 512 + cols[n]] = fmaxf(v, 0.f);
        }
      }
  }
}

// ---------- visual fp32 -> bf16 (VISB) + prefill NIN[:,0:512] ----------
__global__ __launch_bounds__(256) void cvt_vis_k(const float* vis, uint16_t* VISB,
                                                 uint16_t* NIN) {
  const int idx = blockIdx.x * 256 + threadIdx.x;
  const int base = idx * 8;
  const int row = base >> 9, col = base & 511;
  const float4 f0 = *(const float4*)(vis + base);
  const float4 f1 = *(const float4*)(vis + base + 4);
  u32x4 u;
  u[0] = pk2(f0.x, f0.y); u[1] = pk2(f0.z, f0.w);
  u[2] = pk2(f1.x, f1.y); u[3] = pk2(f1.z, f1.w);
  *(u32x4*)(VISB + base) = u;
  *(u32x4*)(NIN + (size_t)row * 1024 + col) = u;
}

// ---------- weight transpose+convert: WT[n][k] = bf16(W[k][n]) ----------
__global__ __launch_bounds__(256) void trans_w_k(const float* We, const float* Wn,
                                                 const float* Wp, uint16_t* WT) {
  const int z = blockIdx.z;
  const float* src; uint16_t* dst; int ldo = 512, koff = 0;
  switch (z) {
    default:
    case 0: src = We;          dst = WT;           break;
    case 1: src = We + 262144; dst = WT + 262144;  break;
    case 2: src = We + 524288; dst = WT + 524288;  break;
    case 3: src = Wn;          dst = WT + 786432;  ldo = 1024; break;
    case 4: src = Wn + 262144; dst = WT + 786432;  ldo = 1024; koff = 512; break;
    case 5: src = Wp;          dst = WT + 1310720; break;
    case 6: src = Wp + 262144; dst = WT + 1572864; break;
    case 7: src = Wp + 524288; dst = WT + 1835008; break;
  }
  __shared__ float tile[32][33];
  const int tx = threadIdx.x, ty = threadIdx.y;  // 32 x 8
  const int kb = blockIdx.x * 32, nb = blockIdx.y * 32;
#pragma unroll
  for (int s = 0; s < 4; ++s)
    tile[ty + 8 * s][tx] = src[(size_t)(kb + ty + 8 * s) * 512 + nb + tx];
  __syncthreads();
#pragma unroll
  for (int s = 0; s < 4; ++s) {
    const int n = nb + ty + 8 * s, k = kb + tx;
    dst[(size_t)n * ldo + koff + k] = (uint16_t)f2bf(tile[tx][ty + 8 * s]);
  }
}

// ---------- softmax over 15 incoming edges + aggregate; writes NIN[:,512:] ----------
__global__ __launch_bounds__(256) void node_reduce_k(const float* AATT, const float* battn,
                                                     const uint16_t* EF, const uint16_t* VISB,
                                                     uint16_t* NIN) {
  const int sub = threadIdx.x >> 7;  // 2 nodes per block
  const int t = threadIdx.x & 127;
  const int v = blockIdx.x * 2 + sub;
  const int gph = v >> 4, j = v & 15;
  __shared__ float sa_s[2][16];
  __shared__ float alf_s[2][16];
  __shared__ int eids_s[2][16];
  __shared__ int srcs_s[2][16];
  if (t < 15) {
    const int i = (t < j) ? t : t + 1;
    const int off = (j < i) ? j : (j - 1);
    const int eid = gph * 240 + i * 15 + off;  // DGL src-major edge id
    eids_s[sub][t] = eid;
    srcs_s[sub][t] = gph * 16 + i;
    sa_s[sub][t] = fmaxf(AATT[eid] + battn[0], 0.f);
  }
  __syncthreads();
  float mx = -1e30f;
#pragma unroll
  for (int i = 0; i < 15; ++i) mx = fmaxf(mx, sa_s[sub][i]);
  float den = 0.f;
#pragma unroll
  for (int i = 0; i < 15; ++i) den += expf(sa_s[sub][i] - mx);
  if (t < 15) alf_s[sub][t] = expf(sa_s[sub][t] - mx) / den;
  __syncthreads();
  const int c = t * 4;
  float z0 = 0.f, z1 = 0.f, z2 = 0.f, z3 = 0.f;
#pragma unroll
  for (int i = 0; i < 15; ++i) {
    const float a = alf_s[sub][i];
    const ushort4 e4 = *(const ushort4*)(EF + (size_t)eids_s[sub][i] * 512 + c);
    const ushort4 v4 = *(const ushort4*)(VISB + (size_t)srcs_s[sub][i] * 512 + c);
    z0 += a * (bf2f(e4.x) + bf2f(v4.x)); z1 += a * (bf2f(e4.y) + bf2f(v4.y));
    z2 += a * (bf2f(e4.z) + bf2f(v4.z)); z3 += a * (bf2f(e4.w) + bf2f(v4.w));
  }
  ushort4 o;
  o.x = (unsigned short)f2bf(z0); o.y = (unsigned short)f2bf(z1);
  o.z = (unsigned short)f2bf(z2); o.w = (unsigned short)f2bf(z3);
  *(ushort4*)(NIN + (size_t)v * 1024 + 512 + c) = o;
}

// ---------------- launch ----------------
extern "C" void kernel_launch(void* const* d_in, const int* in_sizes, int n_in,
                              void* d_out, int out_size, void* d_ws, size_t ws_size,
                              hipStream_t stream) {
  const float* visual = (const float*)d_in[0];
  const float* spatial = (const float*)d_in[1];
  const float* W_edge = (const float*)d_in[2];
  const float* b_edge = (const float*)d_in[3];
  const float* W_attn = (const float*)d_in[4];
  const float* b_attn = (const float*)d_in[5];
  const float* W_node = (const float*)d_in[6];
  const float* b_node = (const float*)d_in[7];
  const float* W_pred = (const float*)d_in[8];
  const float* b_pred = (const float*)d_in[9];
  const int* src = (const int*)d_in[10];
  const int* dst = (const int*)d_in[11];
  const int* toe = (const int*)d_in[12];
  float* out = (float*)d_out;

  char* ws = (char*)d_ws;
  uint16_t* WT = (uint16_t*)ws;                    // @0        4 MB
  uint16_t* VISB = (uint16_t*)(ws + 4194304);      // @4MB      4 MB
  uint16_t* NIN = (uint16_t*)(ws + 8388608);       // @8MB      8 MB  [4096][1024]
  uint16_t* A13b = (uint16_t*)(ws + 16777216);     // @16MB     8 MB  [4096][1024]
  uint16_t* EF = (uint16_t*)(ws + 25165824);       // @24MB    60 MB  [61440][512]
  float* AATT = (float*)(ws + 88080384);           // @84MB   240 KB  (end 88,326,144)
  uint16_t* U13b = A13b;   // A13b dead after edge GEMM
  uint16_t* NNF = EF;      // EF dead after node_reduce

  cvt_vis_k<<<1024, 256, 0, stream>>>(visual, VISB, NIN);
  trans_w_k<<<dim3(16, 16, 8), dim3(32, 8), 0, stream>>>(W_edge, W_node, W_pred, WT);
  hipMemsetAsync(AATT, 0, 61440 * sizeof(float), stream);

  const dim3 blk(256);
  {  // A13 = vis_bf16 @ [W1 | W3]  (bf16 out)
    GemmArgs a = {};
    a.Ab = VISB; a.lda = 512; a.B0 = WT; a.B1 = WT + 524288; a.K = 512;
    a.nwg = 256; a.ncol = 8;
    a.C16 = A13b; a.ldc = 1024;
    gemm_k<A_LDS, E_PLAIN16><<<256, blk, 0, stream>>>(a);
  }
  {  // e_f = relu(spatial@W2 + A1[src] + A3[dst] + b); attn partials
    GemmArgs a = {};
    a.Af = spatial; a.B0 = WT + 262144; a.K = 512;
    a.nwg = 1920; a.ncol = 4;
    a.bias = b_edge; a.wattn = W_attn;
    a.src = src; a.dst = dst; a.A13 = A13b; a.EF = EF; a.AATT = AATT;
    gemm_k<A_REG, E_EDGE><<<1920, blk, 0, stream>>>(a);
  }
  node_reduce_k<<<2048, blk, 0, stream>>>(AATT, b_attn, EF, VISB, NIN);
  {  // new_n_f = relu(NIN @ W_node + b)  (K=1024)
    GemmArgs a = {};
    a.Ab = NIN; a.lda = 1024; a.B0 = WT + 786432; a.K = 1024;
    a.nwg = 128; a.ncol = 4;
    a.bias = b_node; a.C16 = NNF; a.ldc = 512;
    gemm_k<A_LDS, E_NODE><<<128, blk, 0, stream>>>(a);
  }
  {  // U13 = new_n_f @ [Wp1 | Wp3]
    GemmArgs a = {};
    a.Ab = NNF; a.lda = 512; a.B0 = WT + 1310720; a.B1 = WT + 1835008; a.K = 512;
    a.nwg = 256; a.ncol = 8;
    a.C16 = U13b; a.ldc = 1024;
    gemm_k<A_LDS, E_PLAIN16><<<256, blk, 0, stream>>>(a);
  }
  {  // pred = relu(U1[ts] + spatial[toe]@Wp2 + U3[td] + b)
    GemmArgs a = {};
    a.Af = spatial; a.gidx = toe; a.B0 = WT + 1572864; a.K = 512;
    a.nwg = 120; a.ncol = 4;
    a.bias = b_pred; a.toe = toe; a.src = src; a.dst = dst; a.U13 = U13b; a.OUT = out;
    gemm_k<A_REGGATHER, E_PRED><<<120, blk, 0, stream>>>(a);
  }
  (void)in_sizes; (void)n_in; (void)out_size; (void)ws_size;
}

// Round 6
// 209.747 us; speedup vs baseline: 1.1790x; 1.1790x over previous
//
#include <hip/hip_runtime.h>
#include <hip/hip_bf16.h>
#include <stdint.h>

#define BM 128
#define BN 128

typedef __attribute__((ext_vector_type(8))) short bf16x8;
typedef __attribute__((ext_vector_type(4))) float f32x4;
typedef __attribute__((ext_vector_type(4))) uint32_t u32x4;

__device__ __forceinline__ short f2bf(float f) {
  union { float f; uint32_t u; } v; v.f = f;
  return (short)((v.u + 0x7FFFu + ((v.u >> 16) & 1u)) >> 16);  // RNE
}
__device__ __forceinline__ float bf2f(uint16_t s) {
  union { uint32_t u; float f; } v; v.u = ((uint32_t)s) << 16;
  return v.f;
}
__device__ __forceinline__ uint32_t pk2(float lo, float hi) {
  union { __hip_bfloat162 h; uint32_t u; } un;
  un.h = __float22bfloat162_rn(make_float2(lo, hi));  // v_cvt_pk_bf16_f32
  return un.u;
}
__device__ __forceinline__ void gload_lds16(const void* g, void* l) {
  __builtin_amdgcn_global_load_lds((const __attribute__((address_space(1))) void*)g,
                                   (__attribute__((address_space(3))) void*)l, 16, 0, 0);
}
// bijective XCD-chunk swizzle (m204)
__device__ __forceinline__ int xcd_swz(int d, int n) {
  const int q = n >> 3, r = n & 7, x = d & 7, i = d >> 3;
  return (x < r ? x * (q + 1) : r * (q + 1) + (x - r) * q) + i;
}

enum { A_LDS = 0, A_REG = 1 };
enum { E_PLAIN16 = 0, E_EDGE = 1, E_NODE = 2, E_PRED = 3 };

struct GemmArgs {
  const uint16_t* Ab; int lda;   // A_LDS: bf16 A
  const float* Af;               // A_REG: fp32 A (lda=512)
  const int* gidx;               // optional row gather (either mode)
  const uint16_t* B0;            // B^T bf16 [N][K]; out cols < 512
  const uint16_t* B1;            // out cols >= 512
  int K;
  int nwg, ncol;                 // 1-D grid decomposition (col-fastest)
  uint16_t* C16; int ldc;        // bf16 output
  const float* bias;
  const float* wattn;
  const int* src; const int* dst; const int* toe;
  const uint16_t* A13;           // bf16 [4096][1024]
  const uint16_t* U13;           // bf16 [4096][1024]
  uint16_t* EF;                  // e_f bf16 [61440][512]
  float* AATT;                   // attn partials [61440]
  float* OUT;                    // pred fp32 [3840][512]
};

template <int AMODE, int EPI>
__global__ __launch_bounds__(256) void gemm_k(GemmArgs g) {
  __shared__ __align__(16) short As[2][4096];  // [h][row*32 + k]
  __shared__ __align__(16) short Bs[2][4096];
  __shared__ __align__(16) short a13s[(EPI == E_EDGE) ? 8192 : 16];  // 32 nodes x 256
  const int tid = threadIdx.x, w = tid >> 6, lane = tid & 63;

  const int sid = xcd_swz(blockIdx.x, g.nwg);
  const int colb = sid % g.ncol, rowb = sid / g.ncol;
  const int m0 = rowb * BM, n0g = colb * BN;

  const uint16_t* Bp = g.B0; int n0 = n0g;
  if (n0g >= 512) { Bp = g.B1; n0 = n0g - 512; }

  // ---- global_load_lds geometry (16B/lane, linear wave-uniform dest) ----
  const int gr = lane >> 2, gk = (lane & 3) * 8;
  const uint16_t* gB0 = Bp + (size_t)(n0 + w * 16 + gr) * g.K + gk;
  const uint16_t* gB1 = gB0 + (size_t)64 * g.K;
  const int cofs0 = (w * 16) * 32;
  const int cofs1 = (64 + w * 16) * 32;

  const uint16_t* gA0 = nullptr; const uint16_t* gA1 = nullptr;
  const float* arow = nullptr; int aofs = 0;
  if constexpr (AMODE == A_LDS) {
    int r0 = m0 + w * 16 + gr, r1 = r0 + 64;
    if (g.gidx) { r0 = g.gidx[r0]; r1 = g.gidx[r1]; }
    gA0 = g.Ab + (size_t)r0 * g.lda + gk;
    gA1 = g.Ab + (size_t)r1 * g.lda + gk;
  } else {
    const int tr = tid >> 1, ch = tid & 1;
    int row = m0 + tr;
    if (g.gidx) row = g.gidx[row];
    arow = g.Af + (size_t)row * 512 + ch * 16;
    aofs = tr * 32 + ch * 16;
  }

  // ---- E_EDGE prologue: stage the block's 32 A13-node slices into LDS ----
  // (drained by the first __syncthreads; consumed only in the epilogue)
  int vb = 0;
  if constexpr (EPI == E_EDGE) {
    vb = (m0 / 240) * 16;  // first graph's node base; block spans <= 2 graphs
    const int inner = lane & 31;
    const int colg = (inner < 16) ? (n0g + inner * 8) : (512 + n0g + (inner - 16) * 8);
    const uint16_t* abase = g.A13 + (size_t)(vb + w * 8 + (lane >> 5)) * 1024 + colg;
#pragma unroll
    for (int rd = 0; rd < 4; ++rd)
      gload_lds16(abase + (size_t)rd * 2048, &a13s[(w * 8 + rd * 2) * 256]);
  }

  const int wm = w >> 1, wn = w & 1;
  const int lr = lane & 15, lg = lane >> 4;
  int aro[4], bro[4];
#pragma unroll
  for (int m = 0; m < 4; ++m) aro[m] = (wm * 64 + m * 16 + lr) * 32 + lg * 8;
#pragma unroll
  for (int n = 0; n < 4; ++n) bro[n] = (wn * 64 + n * 16 + lr) * 32 + lg * 8;

  f32x4 acc[4][4] = {};

  for (int k0 = 0; k0 < g.K; k0 += 64) {
    __syncthreads();
#pragma unroll
    for (int h = 0; h < 2; ++h) {
      const int kk = k0 + h * 32;
      gload_lds16(gB0 + kk, &Bs[h][cofs0]);
      gload_lds16(gB1 + kk, &Bs[h][cofs1]);
      if constexpr (AMODE == A_LDS) {
        gload_lds16(gA0 + kk, &As[h][cofs0]);
        gload_lds16(gA1 + kk, &As[h][cofs1]);
      } else {
        const float* p = arow + kk;
        const float4 f0 = *(const float4*)(p);
        const float4 f1 = *(const float4*)(p + 4);
        const float4 f2 = *(const float4*)(p + 8);
        const float4 f3 = *(const float4*)(p + 12);
        u32x4 lo, hi;
        lo[0] = pk2(f0.x, f0.y); lo[1] = pk2(f0.z, f0.w);
        lo[2] = pk2(f1.x, f1.y); lo[3] = pk2(f1.z, f1.w);
        hi[0] = pk2(f2.x, f2.y); hi[1] = pk2(f2.z, f2.w);
        hi[2] = pk2(f3.x, f3.y); hi[3] = pk2(f3.z, f3.w);
        *(u32x4*)&As[h][aofs] = lo;
        *(u32x4*)&As[h][aofs + 8] = hi;
      }
    }
    __syncthreads();
#pragma unroll
    for (int h = 0; h < 2; ++h) {
      bf16x8 av[4], bv[4];
#pragma unroll
      for (int m = 0; m < 4; ++m) av[m] = *(const bf16x8*)&As[h][aro[m]];
#pragma unroll
      for (int n = 0; n < 4; ++n) bv[n] = *(const bf16x8*)&Bs[h][bro[n]];
#pragma unroll
      for (int m = 0; m < 4; ++m)
#pragma unroll
        for (int n = 0; n < 4; ++n)
          acc[m][n] = __builtin_amdgcn_mfma_f32_16x16x32_bf16(av[m], bv[n], acc[m][n], 0, 0, 0);
    }
  }

  // ---- epilogue ----  C/D: col = lane&15, row = (lane>>4)*4 + reg
  const int rbase = m0 + wm * 64;
  const int cbase = n0g + wn * 64;

  if constexpr (EPI == E_PLAIN16) {
#pragma unroll
    for (int m = 0; m < 4; ++m)
#pragma unroll
      for (int r = 0; r < 4; ++r) {
        const int row = rbase + m * 16 + lg * 4 + r;
#pragma unroll
        for (int n = 0; n < 4; ++n)
          g.C16[(size_t)row * g.ldc + cbase + n * 16 + lr] = (uint16_t)f2bf(acc[m][n][r]);
      }
  } else if constexpr (EPI == E_NODE) {
#pragma unroll
    for (int m = 0; m < 4; ++m)
#pragma unroll
      for (int r = 0; r < 4; ++r) {
        const int row = rbase + m * 16 + lg * 4 + r;
#pragma unroll
        for (int n = 0; n < 4; ++n) {
          const int col = cbase + n * 16 + lr;
          const float v = fmaxf(acc[m][n][r] + g.bias[col], 0.f);
          g.C16[(size_t)row * g.ldc + col] = (uint16_t)f2bf(v);
        }
      }
  } else if constexpr (EPI == E_EDGE) {
    float bv[4], wv[4]; int lc[4];
#pragma unroll
    for (int n = 0; n < 4; ++n) {
      lc[n] = wn * 64 + n * 16 + lr;          // col within this block's 128
      bv[n] = g.bias[n0g + lc[n]];
      wv[n] = g.wattn[n0g + lc[n]];
    }
#pragma unroll
    for (int m = 0; m < 4; ++m)
#pragma unroll
      for (int r = 0; r < 4; ++r) {
        const int e = rbase + m * 16 + lg * 4 + r;
        const int se = g.src[e] - vb, de = g.dst[e] - vb;  // local node ids [0,32)
        float rp = 0.f;
#pragma unroll
        for (int n = 0; n < 4; ++n) {
          float v = acc[m][n][r] + bf2f((uint16_t)a13s[se * 256 + lc[n]]) +
                    bf2f((uint16_t)a13s[de * 256 + 128 + lc[n]]) + bv[n];
          v = fmaxf(v, 0.f);
          rp += v * wv[n];
          g.EF[(size_t)e * 512 + n0g + lc[n]] = (uint16_t)f2bf(v);
        }
        for (int d = 1; d < 16; d <<= 1) rp += __shfl_xor(rp, d);
        if (lr == 0) atomicAdd(&g.AATT[e], rp);
      }
  } else {  // E_PRED
    float bv[4]; int cols[4];
#pragma unroll
    for (int n = 0; n < 4; ++n) { cols[n] = cbase + n * 16 + lr; bv[n] = g.bias[cols[n]]; }
#pragma unroll
    for (int m = 0; m < 4; ++m)
#pragma unroll
      for (int r = 0; r < 4; ++r) {
        const int row = rbase + m * 16 + lg * 4 + r;
        const int te = g.toe[row];
        const int ts = g.src[te], td = g.dst[te];
        const uint16_t* u1 = g.U13 + (size_t)ts * 1024;
        const uint16_t* u3 = g.U13 + (size_t)td * 1024 + 512;
#pragma unroll
        for (int n = 0; n < 4; ++n) {
          const float v = acc[m][n][r] + bf2f(u1[cols[n]]) + bf2f(u3[cols[n]]) + bv[n];
          g.OUT[(size_t)row * 512 + cols[n]] = fmaxf(v, 0.f);
        }
      }
  }
}

// ---------- generic fp32 -> bf16 (grid-stride, 8/thread) ----------
__global__ __launch_bounds__(256) void cvt_f32bf16_k(const float* in, uint16_t* out, int n8) {
  for (int i = blockIdx.x * 256 + threadIdx.x; i < n8; i += gridDim.x * 256) {
    const int base = i * 8;
    const float4 f0 = *(const float4*)(in + base);
    const float4 f1 = *(const float4*)(in + base + 4);
    u32x4 u;
    u[0] = pk2(f0.x, f0.y); u[1] = pk2(f0.z, f0.w);
    u[2] = pk2(f1.x, f1.y); u[3] = pk2(f1.z, f1.w);
    *(u32x4*)(out + base) = u;
  }
}

// ---------- visual fp32 -> bf16 (VISB) + prefill NIN[:,0:512] ----------
__global__ __launch_bounds__(256) void cvt_vis_k(const float* vis, uint16_t* VISB,
                                                 uint16_t* NIN) {
  const int idx = blockIdx.x * 256 + threadIdx.x;
  const int base = idx * 8;
  const int row = base >> 9, col = base & 511;
  const float4 f0 = *(const float4*)(vis + base);
  const float4 f1 = *(const float4*)(vis + base + 4);
  u32x4 u;
  u[0] = pk2(f0.x, f0.y); u[1] = pk2(f0.z, f0.w);
  u[2] = pk2(f1.x, f1.y); u[3] = pk2(f1.z, f1.w);
  *(u32x4*)(VISB + base) = u;
  *(u32x4*)(NIN + (size_t)row * 1024 + col) = u;
}

// ---------- weight transpose+convert: WT[n][k] = bf16(W[k][n]) ----------
__global__ __launch_bounds__(256) void trans_w_k(const float* We, const float* Wn,
                                                 const float* Wp, uint16_t* WT) {
  const int z = blockIdx.z;
  const float* src; uint16_t* dst; int ldo = 512, koff = 0;
  switch (z) {
    default:
    case 0: src = We;          dst = WT;           break;
    case 1: src = We + 262144; dst = WT + 262144;  break;
    case 2: src = We + 524288; dst = WT + 524288;  break;
    case 3: src = Wn;          dst = WT + 786432;  ldo = 1024; break;
    case 4: src = Wn + 262144; dst = WT + 786432;  ldo = 1024; koff = 512; break;
    case 5: src = Wp;          dst = WT + 1310720; break;
    case 6: src = Wp + 262144; dst = WT + 1572864; break;
    case 7: src = Wp + 524288; dst = WT + 1835008; break;
  }
  __shared__ float tile[32][33];
  const int tx = threadIdx.x, ty = threadIdx.y;  // 32 x 8
  const int kb = blockIdx.x * 32, nb = blockIdx.y * 32;
#pragma unroll
  for (int s = 0; s < 4; ++s)
    tile[ty + 8 * s][tx] = src[(size_t)(kb + ty + 8 * s) * 512 + nb + tx];
  __syncthreads();
#pragma unroll
  for (int s = 0; s < 4; ++s) {
    const int n = nb + ty + 8 * s, k = kb + tx;
    dst[(size_t)n * ldo + koff + k] = (uint16_t)f2bf(tile[tx][ty + 8 * s]);
  }
}

// ---------- softmax over 15 incoming edges + aggregate; writes NIN[:,512:] ----------
__global__ __launch_bounds__(256) void node_reduce_k(const float* AATT, const float* battn,
                                                     const uint16_t* EF, const uint16_t* VISB,
                                                     uint16_t* NIN) {
  const int sub = threadIdx.x >> 7;  // 2 nodes per block
  const int t = threadIdx.x & 127;
  const int v = blockIdx.x * 2 + sub;
  const int gph = v >> 4, j = v & 15;
  __shared__ float sa_s[2][16];
  __shared__ float alf_s[2][16];
  __shared__ int eids_s[2][16];
  __shared__ int srcs_s[2][16];
  if (t < 15) {
    const int i = (t < j) ? t : t + 1;
    const int off = (j < i) ? j : (j - 1);
    const int eid = gph * 240 + i * 15 + off;  // DGL src-major edge id
    eids_s[sub][t] = eid;
    srcs_s[sub][t] = gph * 16 + i;
    sa_s[sub][t] = fmaxf(AATT[eid] + battn[0], 0.f);
  }
  __syncthreads();
  float mx = -1e30f;
#pragma unroll
  for (int i = 0; i < 15; ++i) mx = fmaxf(mx, sa_s[sub][i]);
  float den = 0.f;
#pragma unroll
  for (int i = 0; i < 15; ++i) den += expf(sa_s[sub][i] - mx);
  if (t < 15) alf_s[sub][t] = expf(sa_s[sub][t] - mx) / den;
  __syncthreads();
  const int c = t * 4;
  float z0 = 0.f, z1 = 0.f, z2 = 0.f, z3 = 0.f;
#pragma unroll
  for (int i = 0; i < 15; ++i) {
    const float a = alf_s[sub][i];
    const ushort4 e4 = *(const ushort4*)(EF + (size_t)eids_s[sub][i] * 512 + c);
    const ushort4 v4 = *(const ushort4*)(VISB + (size_t)srcs_s[sub][i] * 512 + c);
    z0 += a * (bf2f(e4.x) + bf2f(v4.x)); z1 += a * (bf2f(e4.y) + bf2f(v4.y));
    z2 += a * (bf2f(e4.z) + bf2f(v4.z)); z3 += a * (bf2f(e4.w) + bf2f(v4.w));
  }
  ushort4 o;
  o.x = (unsigned short)f2bf(z0); o.y = (unsigned short)f2bf(z1);
  o.z = (unsigned short)f2bf(z2); o.w = (unsigned short)f2bf(z3);
  *(ushort4*)(NIN + (size_t)v * 1024 + 512 + c) = o;
}

// ---------------- launch ----------------
extern "C" void kernel_launch(void* const* d_in, const int* in_sizes, int n_in,
                              void* d_out, int out_size, void* d_ws, size_t ws_size,
                              hipStream_t stream) {
  const float* visual = (const float*)d_in[0];
  const float* spatial = (const float*)d_in[1];
  const float* W_edge = (const float*)d_in[2];
  const float* b_edge = (const float*)d_in[3];
  const float* W_attn = (const float*)d_in[4];
  const float* b_attn = (const float*)d_in[5];
  const float* W_node = (const float*)d_in[6];
  const float* b_node = (const float*)d_in[7];
  const float* W_pred = (const float*)d_in[8];
  const float* b_pred = (const float*)d_in[9];
  const int* src = (const int*)d_in[10];
  const int* dst = (const int*)d_in[11];
  const int* toe = (const int*)d_in[12];
  float* out = (float*)d_out;

  char* ws = (char*)d_ws;
  uint16_t* WT = (uint16_t*)ws;                    // @0        4 MB
  uint16_t* VISB = (uint16_t*)(ws + 4194304);      // @4MB      4 MB
  uint16_t* NIN = (uint16_t*)(ws + 8388608);       // @8MB      8 MB  [4096][1024]
  uint16_t* A13b = (uint16_t*)(ws + 16777216);     // @16MB     8 MB  [4096][1024]
  uint16_t* EF = (uint16_t*)(ws + 25165824);       // @24MB    60 MB  [61440][512]
  float* AATT = (float*)(ws + 88080384);           // @84MB   240 KB
  uint16_t* SPB = (uint16_t*)(ws + 88326144);      // @~84.2MB 60 MB (optional)
  const bool spb_ok = ws_size >= 151240704ull;
  uint16_t* U13b = A13b;   // A13b dead after edge GEMM
  uint16_t* NNF = EF;      // EF dead after node_reduce

  cvt_vis_k<<<1024, 256, 0, stream>>>(visual, VISB, NIN);
  if (spb_ok) cvt_f32bf16_k<<<4096, 256, 0, stream>>>(spatial, SPB, 3932160);
  trans_w_k<<<dim3(16, 16, 8), dim3(32, 8), 0, stream>>>(W_edge, W_node, W_pred, WT);
  hipMemsetAsync(AATT, 0, 61440 * sizeof(float), stream);

  const dim3 blk(256);
  {  // A13 = vis_bf16 @ [W1 | W3]  (bf16 out)
    GemmArgs a = {};
    a.Ab = VISB; a.lda = 512; a.B0 = WT; a.B1 = WT + 524288; a.K = 512;
    a.nwg = 256; a.ncol = 8;
    a.C16 = A13b; a.ldc = 1024;
    gemm_k<A_LDS, E_PLAIN16><<<256, blk, 0, stream>>>(a);
  }
  {  // e_f = relu(spatial@W2 + A1[src] + A3[dst] + b); attn partials
    GemmArgs a = {};
    a.B0 = WT + 262144; a.K = 512;
    a.nwg = 1920; a.ncol = 4;
    a.bias = b_edge; a.wattn = W_attn;
    a.src = src; a.dst = dst; a.A13 = A13b; a.EF = EF; a.AATT = AATT;
    if (spb_ok) {
      a.Ab = SPB; a.lda = 512;
      gemm_k<A_LDS, E_EDGE><<<1920, blk, 0, stream>>>(a);
    } else {
      a.Af = spatial;
      gemm_k<A_REG, E_EDGE><<<1920, blk, 0, stream>>>(a);
    }
  }
  node_reduce_k<<<2048, blk, 0, stream>>>(AATT, b_attn, EF, VISB, NIN);
  {  // new_n_f = relu(NIN @ W_node + b)  (K=1024)
    GemmArgs a = {};
    a.Ab = NIN; a.lda = 1024; a.B0 = WT + 786432; a.K = 1024;
    a.nwg = 128; a.ncol = 4;
    a.bias = b_node; a.C16 = NNF; a.ldc = 512;
    gemm_k<A_LDS, E_NODE><<<128, blk, 0, stream>>>(a);
  }
  {  // U13 = new_n_f @ [Wp1 | Wp3]
    GemmArgs a = {};
    a.Ab = NNF; a.lda = 512; a.B0 = WT + 1310720; a.B1 = WT + 1835008; a.K = 512;
    a.nwg = 256; a.ncol = 8;
    a.C16 = U13b; a.ldc = 1024;
    gemm_k<A_LDS, E_PLAIN16><<<256, blk, 0, stream>>>(a);
  }
  {  // pred = relu(U1[ts] + spatial[toe]@Wp2 + U3[td] + b)
    GemmArgs a = {};
    a.B0 = WT + 1572864; a.K = 512;
    a.nwg = 120; a.ncol = 4;
    a.bias = b_pred; a.toe = toe; a.src = src; a.dst = dst; a.U13 = U13b; a.OUT = out;
    a.gidx = toe;
    if (spb_ok) {
      a.Ab = SPB; a.lda = 512;
      gemm_k<A_LDS, E_PRED><<<120, blk, 0, stream>>>(a);
    } else {
      a.Af = spatial;
      gemm_k<A_REG, E_PRED><<<120, blk, 0, stream>>>(a);
    }
  }
  (void)in_sizes; (void)n_in; (void)out_size;
}

// Round 7
// 199.705 us; speedup vs baseline: 1.2383x; 1.0503x over previous
//
#include <hip/hip_runtime.h>
#include <hip/hip_bf16.h>
#include <stdint.h>

#define BM 128
#define BN 128

typedef __attribute__((ext_vector_type(8))) short bf16x8;
typedef __attribute__((ext_vector_type(4))) float f32x4;
typedef __attribute__((ext_vector_type(4))) uint32_t u32x4;

__device__ __forceinline__ short f2bf(float f) {
  union { float f; uint32_t u; } v; v.f = f;
  return (short)((v.u + 0x7FFFu + ((v.u >> 16) & 1u)) >> 16);  // RNE
}
__device__ __forceinline__ float bf2f(uint16_t s) {
  union { uint32_t u; float f; } v; v.u = ((uint32_t)s) << 16;
  return v.f;
}
__device__ __forceinline__ uint32_t pk2(float lo, float hi) {
  union { __hip_bfloat162 h; uint32_t u; } un;
  un.h = __float22bfloat162_rn(make_float2(lo, hi));  // v_cvt_pk_bf16_f32
  return un.u;
}
__device__ __forceinline__ void gload_lds16(const void* g, void* l) {
  __builtin_amdgcn_global_load_lds((const __attribute__((address_space(1))) void*)g,
                                   (__attribute__((address_space(3))) void*)l, 16, 0, 0);
}
// bijective XCD-chunk swizzle (m204)
__device__ __forceinline__ int xcd_swz(int d, int n) {
  const int q = n >> 3, r = n & 7, x = d & 7, i = d >> 3;
  return (x < r ? x * (q + 1) : r * (q + 1) + (x - r) * q) + i;
}

enum { A_LDS = 0, A_REG = 1 };
enum { E_PLAIN16 = 0, E_EDGE = 1, E_NODE = 2, E_PRED = 3 };

struct GemmArgs {
  const uint16_t* Ab; int lda;   // A_LDS: bf16 A
  const float* Af;               // A_REG: fp32 A (lda=512)
  const int* gidx;               // optional row gather (either mode)
  const uint16_t* B0;            // B^T bf16 [N][K]; out cols < 512
  const uint16_t* B1;            // out cols >= 512
  int K;
  int nwg, ncol;                 // 1-D grid decomposition (col-fastest)
  uint16_t* C16; int ldc;        // bf16 output
  const float* bias;
  const float* wattn;
  const int* src; const int* dst; const int* toe;
  const uint16_t* A13;           // bf16 [4096][1024]
  const uint16_t* U13;           // bf16 [4096][1024]
  uint16_t* EF;                  // e_f bf16 [61440][512]
  float* AATT;                   // attn partials [61440]
  float* OUT;                    // pred fp32 [3840][512]
};

// BK=32, single-buffered 16KB As+Bs (m97 layout): stage -> drain -> 16 MFMA.
// Latency hidden by TLP: 32KB LDS/block (E_EDGE) -> 5 blocks/CU.
template <int AMODE, int EPI>
__global__ __launch_bounds__(256) void gemm_k(GemmArgs g) {
  __shared__ __align__(16) short As[4096];  // [row][k] 128x32
  __shared__ __align__(16) short Bs[4096];
  __shared__ __align__(16) short a13s[(EPI == E_EDGE) ? 8192 : 16];  // 32 nodes x 256
  const int tid = threadIdx.x, w = tid >> 6, lane = tid & 63;

  const int sid = xcd_swz(blockIdx.x, g.nwg);
  const int colb = sid % g.ncol, rowb = sid / g.ncol;
  const int m0 = rowb * BM, n0g = colb * BN;

  const uint16_t* Bp = g.B0; int n0 = n0g;
  if (n0g >= 512) { Bp = g.B1; n0 = n0g - 512; }

  // ---- global_load_lds geometry (16B/lane, linear wave-uniform dest) ----
  const int gr = lane >> 2, gk = (lane & 3) * 8;
  const uint16_t* gB0 = Bp + (size_t)(n0 + w * 16 + gr) * g.K + gk;
  const uint16_t* gB1 = gB0 + (size_t)64 * g.K;
  const int cofs0 = (w * 16) * 32;
  const int cofs1 = (64 + w * 16) * 32;

  const uint16_t* gA0 = nullptr; const uint16_t* gA1 = nullptr;
  const float* arow = nullptr; int aofs = 0;
  if constexpr (AMODE == A_LDS) {
    int r0 = m0 + w * 16 + gr, r1 = r0 + 64;
    if (g.gidx) { r0 = g.gidx[r0]; r1 = g.gidx[r1]; }
    gA0 = g.Ab + (size_t)r0 * g.lda + gk;
    gA1 = g.Ab + (size_t)r1 * g.lda + gk;
  } else {
    const int tr = tid >> 1, ch = tid & 1;
    int row = m0 + tr;
    if (g.gidx) row = g.gidx[row];
    arow = g.Af + (size_t)row * 512 + ch * 16;
    aofs = tr * 32 + ch * 16;
  }

  // ---- E_EDGE prologue: stage the block's 32 A13-node slices into LDS ----
  int vb = 0;
  if constexpr (EPI == E_EDGE) {
    vb = (m0 / 240) * 16;  // first graph's node base; block spans <= 2 graphs
    const int inner = lane & 31;
    const int colg = (inner < 16) ? (n0g + inner * 8) : (512 + n0g + (inner - 16) * 8);
    const uint16_t* abase = g.A13 + (size_t)(vb + w * 8 + (lane >> 5)) * 1024 + colg;
#pragma unroll
    for (int rd = 0; rd < 4; ++rd)
      gload_lds16(abase + (size_t)rd * 2048, &a13s[(w * 8 + rd * 2) * 256]);
  }

  const int wm = w >> 1, wn = w & 1;
  const int lr = lane & 15, lg = lane >> 4;
  int aro[4], bro[4];
#pragma unroll
  for (int m = 0; m < 4; ++m) aro[m] = (wm * 64 + m * 16 + lr) * 32 + lg * 8;
#pragma unroll
  for (int n = 0; n < 4; ++n) bro[n] = (wn * 64 + n * 16 + lr) * 32 + lg * 8;

  f32x4 acc[4][4] = {};

  for (int k0 = 0; k0 < g.K; k0 += 32) {
    __syncthreads();  // LDS reuse guard
    gload_lds16(gB0 + k0, &Bs[cofs0]);
    gload_lds16(gB1 + k0, &Bs[cofs1]);
    if constexpr (AMODE == A_LDS) {
      gload_lds16(gA0 + k0, &As[cofs0]);
      gload_lds16(gA1 + k0, &As[cofs1]);
    } else {
      const float* p = arow + k0;
      const float4 f0 = *(const float4*)(p);
      const float4 f1 = *(const float4*)(p + 4);
      const float4 f2 = *(const float4*)(p + 8);
      const float4 f3 = *(const float4*)(p + 12);
      u32x4 lo, hi;
      lo[0] = pk2(f0.x, f0.y); lo[1] = pk2(f0.z, f0.w);
      lo[2] = pk2(f1.x, f1.y); lo[3] = pk2(f1.z, f1.w);
      hi[0] = pk2(f2.x, f2.y); hi[1] = pk2(f2.z, f2.w);
      hi[2] = pk2(f3.x, f3.y); hi[3] = pk2(f3.z, f3.w);
      *(u32x4*)&As[aofs] = lo;
      *(u32x4*)&As[aofs + 8] = hi;
    }
    __syncthreads();  // drain stage
    bf16x8 av[4], bv[4];
#pragma unroll
    for (int m = 0; m < 4; ++m) av[m] = *(const bf16x8*)&As[aro[m]];
#pragma unroll
    for (int n = 0; n < 4; ++n) bv[n] = *(const bf16x8*)&Bs[bro[n]];
#pragma unroll
    for (int m = 0; m < 4; ++m)
#pragma unroll
      for (int n = 0; n < 4; ++n)
        acc[m][n] = __builtin_amdgcn_mfma_f32_16x16x32_bf16(av[m], bv[n], acc[m][n], 0, 0, 0);
  }

  // ---- epilogue ----  C/D: col = lane&15, row = (lane>>4)*4 + reg
  const int rbase = m0 + wm * 64;
  const int cbase = n0g + wn * 64;

  if constexpr (EPI == E_PLAIN16) {
#pragma unroll
    for (int m = 0; m < 4; ++m)
#pragma unroll
      for (int r = 0; r < 4; ++r) {
        const int row = rbase + m * 16 + lg * 4 + r;
#pragma unroll
        for (int n = 0; n < 4; ++n)
          g.C16[(size_t)row * g.ldc + cbase + n * 16 + lr] = (uint16_t)f2bf(acc[m][n][r]);
      }
  } else if constexpr (EPI == E_NODE) {
#pragma unroll
    for (int m = 0; m < 4; ++m)
#pragma unroll
      for (int r = 0; r < 4; ++r) {
        const int row = rbase + m * 16 + lg * 4 + r;
#pragma unroll
        for (int n = 0; n < 4; ++n) {
          const int col = cbase + n * 16 + lr;
          const float v = fmaxf(acc[m][n][r] + g.bias[col], 0.f);
          g.C16[(size_t)row * g.ldc + col] = (uint16_t)f2bf(v);
        }
      }
  } else if constexpr (EPI == E_EDGE) {
    float bv[4], wv[4]; int lc[4];
#pragma unroll
    for (int n = 0; n < 4; ++n) {
      lc[n] = wn * 64 + n * 16 + lr;          // col within this block's 128
      bv[n] = g.bias[n0g + lc[n]];
      wv[n] = g.wattn[n0g + lc[n]];
    }
#pragma unroll
    for (int m = 0; m < 4; ++m)
#pragma unroll
      for (int r = 0; r < 4; ++r) {
        const int e = rbase + m * 16 + lg * 4 + r;
        const int se = g.src[e] - vb, de = g.dst[e] - vb;  // local node ids [0,32)
        float rp = 0.f;
#pragma unroll
        for (int n = 0; n < 4; ++n) {
          float v = acc[m][n][r] + bf2f((uint16_t)a13s[se * 256 + lc[n]]) +
                    bf2f((uint16_t)a13s[de * 256 + 128 + lc[n]]) + bv[n];
          v = fmaxf(v, 0.f);
          rp += v * wv[n];
          g.EF[(size_t)e * 512 + n0g + lc[n]] = (uint16_t)f2bf(v);
        }
        for (int d = 1; d < 16; d <<= 1) rp += __shfl_xor(rp, d);
        if (lr == 0) atomicAdd(&g.AATT[e], rp);
      }
  } else {  // E_PRED
    float bv[4]; int cols[4];
#pragma unroll
    for (int n = 0; n < 4; ++n) { cols[n] = cbase + n * 16 + lr; bv[n] = g.bias[cols[n]]; }
#pragma unroll
    for (int m = 0; m < 4; ++m)
#pragma unroll
      for (int r = 0; r < 4; ++r) {
        const int row = rbase + m * 16 + lg * 4 + r;
        const int te = g.toe[row];
        const int ts = g.src[te], td = g.dst[te];
        const uint16_t* u1 = g.U13 + (size_t)ts * 1024;
        const uint16_t* u3 = g.U13 + (size_t)td * 1024 + 512;
#pragma unroll
        for (int n = 0; n < 4; ++n) {
          const float v = acc[m][n][r] + bf2f(u1[cols[n]]) + bf2f(u3[cols[n]]) + bv[n];
          g.OUT[(size_t)row * 512 + cols[n]] = fmaxf(v, 0.f);
        }
      }
  }
}

// ---------- fused prep: cvt spatial->SPB | cvt vis->VISB+NIN | W transpose | AATT=0 ----------
__global__ __launch_bounds__(256) void prep_k(const float* spatial, const float* vis,
                                              const float* We, const float* Wn,
                                              const float* Wp, uint16_t* SPB,
                                              uint16_t* VISB, uint16_t* NIN,
                                              uint16_t* WT, float* AATT) {
  __shared__ float tile[32][33];
  const int b = blockIdx.x, tid = threadIdx.x;
  if (b < 4096) {               // spatial fp32 -> bf16 (61440*512 elems)
    if (SPB) {
      for (int i = b * 256 + tid; i < 3932160; i += 4096 * 256) {
        const int base = i * 8;
        const float4 f0 = *(const float4*)(spatial + base);
        const float4 f1 = *(const float4*)(spatial + base + 4);
        u32x4 u;
        u[0] = pk2(f0.x, f0.y); u[1] = pk2(f0.z, f0.w);
        u[2] = pk2(f1.x, f1.y); u[3] = pk2(f1.z, f1.w);
        *(u32x4*)(SPB + base) = u;
      }
    }
  } else if (b < 5120) {        // visual -> VISB + NIN[:,0:512]
    const int base = ((b - 4096) * 256 + tid) * 8;
    const int row = base >> 9, col = base & 511;
    const float4 f0 = *(const float4*)(vis + base);
    const float4 f1 = *(const float4*)(vis + base + 4);
    u32x4 u;
    u[0] = pk2(f0.x, f0.y); u[1] = pk2(f0.z, f0.w);
    u[2] = pk2(f1.x, f1.y); u[3] = pk2(f1.z, f1.w);
    *(u32x4*)(VISB + base) = u;
    *(u32x4*)(NIN + (size_t)row * 1024 + col) = u;
  } else if (b < 7168) {        // weight transpose+cvt: WT[n][k] = bf16(W[k][n])
    const int zb = b - 5120, z = zb >> 8, rem = zb & 255;
    const float* srcp; uint16_t* dstp; int ldo = 512, koff = 0;
    switch (z) {
      default:
      case 0: srcp = We;          dstp = WT;           break;
      case 1: srcp = We + 262144; dstp = WT + 262144;  break;
      case 2: srcp = We + 524288; dstp = WT + 524288;  break;
      case 3: srcp = Wn;          dstp = WT + 786432;  ldo = 1024; break;
      case 4: srcp = Wn + 262144; dstp = WT + 786432;  ldo = 1024; koff = 512; break;
      case 5: srcp = Wp;          dstp = WT + 1310720; break;
      case 6: srcp = Wp + 262144; dstp = WT + 1572864; break;
      case 7: srcp = Wp + 524288; dstp = WT + 1835008; break;
    }
    const int kb = (rem & 15) * 32, nb = (rem >> 4) * 32;
    const int tx = tid & 31, ty = tid >> 5;
#pragma unroll
    for (int s = 0; s < 4; ++s)
      tile[ty + 8 * s][tx] = srcp[(size_t)(kb + ty + 8 * s) * 512 + nb + tx];
    __syncthreads();
#pragma unroll
    for (int s = 0; s < 4; ++s) {
      const int n = nb + ty + 8 * s, k = kb + tx;
      dstp[(size_t)n * ldo + koff + k] = (uint16_t)f2bf(tile[tx][ty + 8 * s]);
    }
  } else {                      // AATT = 0 (61440 floats)
    const int i = (b - 7168) * 1024 + tid * 4;
    float4 z4; z4.x = z4.y = z4.z = z4.w = 0.f;
    *(float4*)(AATT + i) = z4;
  }
}

// ---------- softmax over 15 incoming edges + aggregate; writes NIN[:,512:] ----------
__global__ __launch_bounds__(256) void node_reduce_k(const float* AATT, const float* battn,
                                                     const uint16_t* EF, const uint16_t* VISB,
                                                     uint16_t* NIN) {
  const int sub = threadIdx.x >> 7;  // 2 nodes per block
  const int t = threadIdx.x & 127;
  const int v = blockIdx.x * 2 + sub;
  const int gph = v >> 4, j = v & 15;
  __shared__ float sa_s[2][16];
  __shared__ float alf_s[2][16];
  __shared__ int eids_s[2][16];
  __shared__ int srcs_s[2][16];
  if (t < 15) {
    const int i = (t < j) ? t : t + 1;
    const int off = (j < i) ? j : (j - 1);
    const int eid = gph * 240 + i * 15 + off;  // DGL src-major edge id
    eids_s[sub][t] = eid;
    srcs_s[sub][t] = gph * 16 + i;
    sa_s[sub][t] = fmaxf(AATT[eid] + battn[0], 0.f);
  }
  __syncthreads();
  float mx = -1e30f;
#pragma unroll
  for (int i = 0; i < 15; ++i) mx = fmaxf(mx, sa_s[sub][i]);
  float den = 0.f;
#pragma unroll
  for (int i = 0; i < 15; ++i) den += expf(sa_s[sub][i] - mx);
  if (t < 15) alf_s[sub][t] = expf(sa_s[sub][t] - mx) / den;
  __syncthreads();
  const int c = t * 4;
  float z0 = 0.f, z1 = 0.f, z2 = 0.f, z3 = 0.f;
#pragma unroll
  for (int i = 0; i < 15; ++i) {
    const float a = alf_s[sub][i];
    const ushort4 e4 = *(const ushort4*)(EF + (size_t)eids_s[sub][i] * 512 + c);
    const ushort4 v4 = *(const ushort4*)(VISB + (size_t)srcs_s[sub][i] * 512 + c);
    z0 += a * (bf2f(e4.x) + bf2f(v4.x)); z1 += a * (bf2f(e4.y) + bf2f(v4.y));
    z2 += a * (bf2f(e4.z) + bf2f(v4.z)); z3 += a * (bf2f(e4.w) + bf2f(v4.w));
  }
  ushort4 o;
  o.x = (unsigned short)f2bf(z0); o.y = (unsigned short)f2bf(z1);
  o.z = (unsigned short)f2bf(z2); o.w = (unsigned short)f2bf(z3);
  *(ushort4*)(NIN + (size_t)v * 1024 + 512 + c) = o;
}

// ---------------- launch ----------------
extern "C" void kernel_launch(void* const* d_in, const int* in_sizes, int n_in,
                              void* d_out, int out_size, void* d_ws, size_t ws_size,
                              hipStream_t stream) {
  const float* visual = (const float*)d_in[0];
  const float* spatial = (const float*)d_in[1];
  const float* W_edge = (const float*)d_in[2];
  const float* b_edge = (const float*)d_in[3];
  const float* W_attn = (const float*)d_in[4];
  const float* b_attn = (const float*)d_in[5];
  const float* W_node = (const float*)d_in[6];
  const float* b_node = (const float*)d_in[7];
  const float* W_pred = (const float*)d_in[8];
  const float* b_pred = (const float*)d_in[9];
  const int* src = (const int*)d_in[10];
  const int* dst = (const int*)d_in[11];
  const int* toe = (const int*)d_in[12];
  float* out = (float*)d_out;

  char* ws = (char*)d_ws;
  uint16_t* WT = (uint16_t*)ws;                    // @0        4 MB
  uint16_t* VISB = (uint16_t*)(ws + 4194304);      // @4MB      4 MB
  uint16_t* NIN = (uint16_t*)(ws + 8388608);       // @8MB      8 MB  [4096][1024]
  uint16_t* A13b = (uint16_t*)(ws + 16777216);     // @16MB     8 MB  [4096][1024]
  uint16_t* EF = (uint16_t*)(ws + 25165824);       // @24MB    60 MB  [61440][512]
  float* AATT = (float*)(ws + 88080384);           // @84MB   240 KB
  uint16_t* SPB = (uint16_t*)(ws + 88326144);      // 60 MB (optional)
  const bool spb_ok = ws_size >= 151240704ull;
  uint16_t* U13b = A13b;   // A13b dead after edge GEMM
  uint16_t* NNF = EF;      // EF dead after node_reduce

  prep_k<<<7228, 256, 0, stream>>>(spatial, visual, W_edge, W_node, W_pred,
                                   spb_ok ? SPB : nullptr, VISB, NIN, WT, AATT);

  const dim3 blk(256);
  {  // A13 = vis_bf16 @ [W1 | W3]  (bf16 out)
    GemmArgs a = {};
    a.Ab = VISB; a.lda = 512; a.B0 = WT; a.B1 = WT + 524288; a.K = 512;
    a.nwg = 256; a.ncol = 8;
    a.C16 = A13b; a.ldc = 1024;
    gemm_k<A_LDS, E_PLAIN16><<<256, blk, 0, stream>>>(a);
  }
  {  // e_f = relu(spatial@W2 + A1[src] + A3[dst] + b); attn partials
    GemmArgs a = {};
    a.B0 = WT + 262144; a.K = 512;
    a.nwg = 1920; a.ncol = 4;
    a.bias = b_edge; a.wattn = W_attn;
    a.src = src; a.dst = dst; a.A13 = A13b; a.EF = EF; a.AATT = AATT;
    if (spb_ok) {
      a.Ab = SPB; a.lda = 512;
      gemm_k<A_LDS, E_EDGE><<<1920, blk, 0, stream>>>(a);
    } else {
      a.Af = spatial;
      gemm_k<A_REG, E_EDGE><<<1920, blk, 0, stream>>>(a);
    }
  }
  node_reduce_k<<<2048, blk, 0, stream>>>(AATT, b_attn, EF, VISB, NIN);
  {  // new_n_f = relu(NIN @ W_node + b)  (K=1024)
    GemmArgs a = {};
    a.Ab = NIN; a.lda = 1024; a.B0 = WT + 786432; a.K = 1024;
    a.nwg = 128; a.ncol = 4;
    a.bias = b_node; a.C16 = NNF; a.ldc = 512;
    gemm_k<A_LDS, E_NODE><<<128, blk, 0, stream>>>(a);
  }
  {  // U13 = new_n_f @ [Wp1 | Wp3]
    GemmArgs a = {};
    a.Ab = NNF; a.lda = 512; a.B0 = WT + 1310720; a.B1 = WT + 1835008; a.K = 512;
    a.nwg = 256; a.ncol = 8;
    a.C16 = U13b; a.ldc = 1024;
    gemm_k<A_LDS, E_PLAIN16><<<256, blk, 0, stream>>>(a);
  }
  {  // pred = relu(U1[ts] + spatial[toe]@Wp2 + U3[td] + b)
    GemmArgs a = {};
    a.B0 = WT + 1572864; a.K = 512;
    a.nwg = 120; a.ncol = 4;
    a.bias = b_pred; a.toe = toe; a.src = src; a.dst = dst; a.U13 = U13b; a.OUT = out;
    a.gidx = toe;
    if (spb_ok) {
      a.Ab = SPB; a.lda = 512;
      gemm_k<A_LDS, E_PRED><<<120, blk, 0, stream>>>(a);
    } else {
      a.Af = spatial;
      gemm_k<A_REG, E_PRED><<<120, blk, 0, stream>>>(a);
    }
  }
  (void)in_sizes; (void)n_in; (void)out_size;
}